// Round 10
// baseline (483.785 us; speedup 1.0000x reference)
//
#include <hip/hip_runtime.h>

#define NXI 384
#define NG  (NXI*NXI)          // 147456 elements per system
#define NSYS 8
#define BPS 32                 // blocks per system
#define NBLK (NSYS*BPS)        // 256 blocks
#define NTHR 512               // proven geometry: ~124 VGPR, zero spill
#define ROWS_PB 12             // rows per block
#define EPB (ROWS_PB*NXI)      // 4608 elements per block
#define EPT (EPB/NTHR)         // 9 elements per thread

// thr = EPS*NX*NY = 1e-9*147456
#define THRC 1.47456e-4f

// ---- workspace layout (all blocks' barrier state in PRIVATE cache lines) ----
// bytes [0, 16K):  flags — one 64B line per block: flag(sys,bs) at u32 index (sys*BPS+bs)*16
// bytes [16K,48K): slots — one 128B record per block: rec(sys,bs)[16 doubles], channel=idx
// bytes [48K,...): ghost rows (v,t,x,p boundary exchanges)

// ---- relaxed agent-scope accessors ----
__device__ __forceinline__ float aloadf(const float* p) {
  return __hip_atomic_load(p, __ATOMIC_RELAXED, __HIP_MEMORY_SCOPE_AGENT);
}
__device__ __forceinline__ void astoref(float* p, float v) {
  __hip_atomic_store(p, v, __ATOMIC_RELAXED, __HIP_MEMORY_SCOPE_AGENT);
}
__device__ __forceinline__ double aloadd(const double* p) {
  return __hip_atomic_load(p, __ATOMIC_RELAXED, __HIP_MEMORY_SCOPE_AGENT);
}
__device__ __forceinline__ void astored(double* p, double v) {
  __hip_atomic_store(p, v, __ATOMIC_RELAXED, __HIP_MEMORY_SCOPE_AGENT);
}

__device__ __forceinline__ double wave_red(double v) {
#pragma unroll
  for (int off = 32; off > 0; off >>= 1) v += __shfl_down(v, off, 64);
  return v;
}

// ---- per-system flag barrier (validated protocol; R8 sticky poll, R9 padding) ----
__device__ __forceinline__ void sys_bar(unsigned* flags, unsigned* phase, int tid, int bs) {
  __atomic_signal_fence(__ATOMIC_SEQ_CST);
  __builtin_amdgcn_s_waitcnt(0);
  __syncthreads();
  const unsigned ph = ++(*phase);
  if (tid == 0) {
    __hip_atomic_store(flags + (size_t)bs * 16, ph, __ATOMIC_RELAXED, __HIP_MEMORY_SCOPE_AGENT);
  }
  if (tid < 64) {
    bool done = false;
    while (true) {
      if (!done) {
        const unsigned f = __hip_atomic_load(flags + (size_t)(tid & 31) * 16,
                                             __ATOMIC_RELAXED, __HIP_MEMORY_SCOPE_AGENT);
        done = (f >= ph);
      }
      if (__ballot(done) == ~0ull) break;
      __builtin_amdgcn_s_sleep(2);
    }
  }
  __syncthreads();
  __atomic_signal_fence(__ATOMIC_SEQ_CST);
}

// ---- fused barrier + slot collection + butterfly (R10) ----
// Each polling lane, on FIRST seeing its block's flag, immediately issues that
// block's slot loads — protocol order (slot stores -> s_waitcnt(0) -> flag
// store) guarantees slots are visible before the flag. The LLC read latency
// thus hides inside the residual wait; butterfly (identical order to shredN ->
// bit-exact) runs on arrived data. out[] valid in wave0 lanes only.
__device__ __forceinline__ void sys_bar_collect(unsigned* flags, unsigned* phase,
                                                int tid, int bs,
                                                const double* slots, int chan0, int n,
                                                int sys, double* out) {
  __atomic_signal_fence(__ATOMIC_SEQ_CST);
  __builtin_amdgcn_s_waitcnt(0);
  __syncthreads();
  const unsigned ph = ++(*phase);
  if (tid == 0) {
    __hip_atomic_store(flags + (size_t)bs * 16, ph, __ATOMIC_RELAXED, __HIP_MEMORY_SCOPE_AGENT);
  }
  if (tid < 64) {
    double v[5];
    const double* rec = slots + (size_t)(sys * BPS + (tid & 31)) * 16;
    bool done = false;
    while (true) {
      if (!done) {
        const unsigned f = __hip_atomic_load(flags + (size_t)(tid & 31) * 16,
                                             __ATOMIC_RELAXED, __HIP_MEMORY_SCOPE_AGENT);
        if (f >= ph) {
          done = true;
#pragma unroll
          for (int q = 0; q < n; q++) v[q] = aloadd(rec + chan0 + q);
        }
      }
      if (__ballot(done) == ~0ull) break;
      __builtin_amdgcn_s_sleep(2);
    }
#pragma unroll
    for (int q = 0; q < n; q++) {
      double x = v[q];
      x += __shfl_xor(x, 1, 64);
      x += __shfl_xor(x, 2, 64);
      x += __shfl_xor(x, 4, 64);
      x += __shfl_xor(x, 8, 64);
      x += __shfl_xor(x, 16, 64);
      out[q] = x;
    }
  }
  __syncthreads();
  __atomic_signal_fence(__ATOMIC_SEQ_CST);
}

// Block-reduce n<=5 doubles into this block's PRIVATE 128B slot record.
// Lane q sums channel q (same order as original tid0 loop -> bit-identical).
// No trailing syncthreads: every call site is immediately followed by a
// barrier whose waitcnt+syncthreads supply the guard (all slot stores are
// wave0's, drained by wave0's s_waitcnt before its flag store).
__device__ __forceinline__ void bredN(const double* v, int n,
                                      double* slots, int chan0,
                                      int sys, int bs, int tid) {
  __shared__ double sred[NTHR/64][5];
  const int wid = tid >> 6, lane = tid & 63;
#pragma unroll
  for (int q = 0; q < n; q++) {
    const double w = wave_red(v[q]);
    if (lane == 0) sred[wid][q] = w;
  }
  __syncthreads();
  if (tid < n) {
    double a = 0.0;
#pragma unroll
    for (int w2 = 0; w2 < NTHR/64; w2++) a += sred[w2][tid];
    astored(slots + (size_t)(sys * BPS + bs) * 16 + (chan0 + tid), a);
  }
}

// Butterfly sums of n channels (bit-exact identical in every lane/block).
// Retained for the cold paths (init S0, restart R2) where all threads consume.
__device__ __forceinline__ void shredN(const double* slots, int chan0, int n,
                                       int sys, int lane, double* out) {
  double v[5];
#pragma unroll
  for (int q = 0; q < n; q++)
    v[q] = aloadd(slots + (size_t)(sys * BPS + (lane & 31)) * 16 + (chan0 + q));
#pragma unroll
  for (int q = 0; q < n; q++) {
    double x = v[q];
    x += __shfl_xor(x, 1, 64);
    x += __shfl_xor(x, 2, 64);
    x += __shfl_xor(x, 4, 64);
    x += __shfl_xor(x, 8, 64);
    x += __shfl_xor(x, 16, 64);
    out[q] = x;
  }
}

__device__ __forceinline__ float froguard(double sq) {
  return sq > 0.0 ? (float)sqrt(sq) : 0.0f;
}

// Compute the 5 stencil coefficients at global (row i, col j).
// c5: 0=boo 1=bmo 2=bom 3=bop 4=bpo
__device__ __forceinline__ void coef5(const float* __restrict__ Vb,
                                      const float* __restrict__ M1b,
                                      const float* __restrict__ M2b,
                                      int i, int j, float* c5) {
  const int a0 = (i - 1 < 0) ? 0 : i - 1;
  const int a2 = (i + 1 > NXI - 1) ? NXI - 1 : i + 1;
  const int b0 = (j - 1 < 0) ? 0 : j - 1;
  const int b2 = (j + 1 > NXI - 1) ? NXI - 1 : j + 1;
  const float vc = Vb[j * NXI + i] + 1.0f;
  const float vu = Vb[j * NXI + a0] + 1.0f;
  const float vd = Vb[j * NXI + a2] + 1.0f;
  const float vl = Vb[b0 * NXI + i] + 1.0f;
  const float vr = Vb[b2 * NXI + i] + 1.0f;
  const float D1A = M1b[j * NXI + i] * ((vd - vc) / (0.5f * (vd + vc)));
  const float D1B = M1b[j * NXI + a0] * ((vc - vu) / (0.5f * (vc + vu)));
  const float D2A = M2b[j * NXI + i] * ((vr - vc) / (0.5f * (vr + vc)));
  const float D2B = M2b[b0 * NXI + i] * ((vc - vl) / (0.5f * (vc + vl)));
  c5[0] = 41.0f - 5.0f * (D1B - D1A) - 5.0f * (D2B - D2A);
  c5[1] = -10.0f - 5.0f * D1B;
  c5[2] = -10.0f - 5.0f * D2B;
  c5[3] = -10.0f + 5.0f * D2A;
  c5[4] = -10.0f + 5.0f * D1A;
}

__global__ __launch_bounds__(NTHR, 1) void bicg_kernel(
    const float* __restrict__ V, const float* __restrict__ M1, const float* __restrict__ M2,
    float* __restrict__ xout, float* __restrict__ wsf) {
  const int blk = blockIdx.x;
  const int sys = blk & (NSYS - 1);
  const int bs  = blk >> 3;
  const int tid = threadIdx.x;
  const int lane = tid & 63;
  const int gr0 = bs * ROWS_PB;

  // ---- LDS (~53 KB): rows -1..12 -> index (r+1)*NXI ----
  __shared__ float slabP[14 * NXI];   // p (own + 1 ghost row/side)
  __shared__ float slabS[14 * NXI];   // s (own + ghost); x staging during restart
  __shared__ float vgh[2 * NXI];      // received v ghosts: [0..NXI)=row -1, rest=row 12
  __shared__ float tgh[2 * NXI];      // received t ghosts
  __shared__ float rgh[2 * NXI];      // maintained r ghosts (recursive, bit-exact)
  __shared__ float bcf[4];            // 0:alpha 1:omega 2:beta 3:r_abs
  __shared__ int   bci[1];            // 0 normal, 1 RES, 2 C3, 3 converged-at-init
  __shared__ float sh_r0abs, sh_rho;
  __shared__ double sh_ss2;

  // ---- workspace (private-line layout; see header comment) ----
  unsigned* flags = (unsigned*)wsf + (size_t)sys * BPS * 16;  // 64B per flag
  double* slots = (double*)(wsf + 4096);                      // 128B record per block
  float* ghv_all = wsf + 12288;                               // [sys][bs][2][NXI] v boundary
  float* ght_all = ghv_all + (size_t)NSYS * BPS * 2 * NXI;    // t boundary
  float* ghx_all = ght_all + (size_t)NSYS * BPS * 2 * NXI;    // x boundary (restart)
  float* ghq_all = ghx_all + (size_t)NSYS * BPS * 2 * NXI;    // p boundary (restart)
  float* ghv = ghv_all + (size_t)sys * BPS * 2 * NXI;
  float* ght = ght_all + (size_t)sys * BPS * 2 * NXI;
  float* ghx = ghx_all + (size_t)sys * BPS * 2 * NXI;
  float* ghq = ghq_all + (size_t)sys * BPS * 2 * NXI;
  float* ghv_own = ghv + (size_t)bs * 2 * NXI;      // [0]=row0, [NXI]=row11
  float* ght_own = ght + (size_t)bs * 2 * NXI;
  float* ghx_own = ghx + (size_t)bs * 2 * NXI;
  float* ghq_own = ghq + (size_t)bs * 2 * NXI;

  unsigned bphase = 0;

  const size_t so = (size_t)sys * NG;
  const float* Vb  = V  + so;
  const float* M1b = M1 + so;
  const float* M2b = M2 + so;
  float* xs = xout + so + (size_t)bs * EPB;

  // ---------- Phase 0: own-element coeffs -> REGISTERS + V-mean partial ----------
  float cboo_r[EPT], cbmo_r[EPT], cbom_r[EPT], cbop_r[EPT], cbpo_r[EPT];
#pragma unroll
  for (int k = 0; k < EPT; k++) {
    const int e = tid + k * NTHR;
    const int lr = e / NXI, c = e - lr * NXI;
    float c5[5];
    coef5(Vb, M1b, M2b, gr0 + lr, c, c5);
    cboo_r[k] = c5[0]; cbmo_r[k] = c5[1]; cbom_r[k] = c5[2];
    cbop_r[k] = c5[3]; cbpo_r[k] = c5[4];
  }
  {
    double vsum = 0.0;
#pragma unroll
    for (int k = 0; k < EPT; k++) vsum += (double)Vb[bs * EPB + tid + k * NTHR];
    bredN(&vsum, 1, slots, 9, sys, bs, tid);
  }
  sys_bar(flags, &bphase, tid, bs);  // S0 (only setup barrier)

  // ---------- Init: x=mb; p=r=r0 = mb - rowsum*mb on own AND ghost rows ----------
  double smb[1]; shredN(slots, 9, 1, sys, lane, smb);
  const float mb = (float)(smb[0] / (double)NG) + 1.0f;
  float preg[EPT], rreg[EPT], r0reg[EPT], vreg[EPT], treg[EPT], xreg[EPT];
#pragma unroll
  for (int k = 0; k < EPT; k++) {
    const int e = tid + k * NTHR;
    const int ce = e + NXI;
    const float ax = (cboo_r[k] + cbmo_r[k] + cbom_r[k] + cbop_r[k] + cbpo_r[k]) * mb;
    const float pn = mb - ax;
    xreg[k] = mb;
    preg[k] = pn; rreg[k] = pn; r0reg[k] = pn;
    slabP[ce] = pn;
  }
  for (int g = tid; g < 2 * NXI; g += NTHR) {
    const bool top = g < NXI;
    if (top ? (bs > 0) : (bs < BPS - 1)) {
      const int c = top ? g : g - NXI;
      const int ci = top ? c : 13 * NXI + c;     // row -1 / row 12 index
      const int gi = top ? gr0 - 1 : gr0 + ROWS_PB;
      float c5[5];
      coef5(Vb, M1b, M2b, gi, c, c5);            // one-time ghost coeff recompute
      const float pn = mb - (c5[0] + c5[1] + c5[2] + c5[3] + c5[4]) * mb;
      slabP[ci] = pn;
      rgh[g] = pn;
    }
  }
  if (tid == 0) { bcf[3] = 1.0f; bci[0] = 0; }

  for (int it = 0; it < 30; ++it) {
    __syncthreads();                 // bcf/slab writes visible
    if (!(bcf[3] > THRC)) break;     // uniform within system

    // ==== P1: v = A p own rows; publish v rows 0/11; 5 dots ====
    {
      double d[5] = {0, 0, 0, 0, 0};
#pragma unroll
      for (int k = 0; k < EPT; k++) {
        const int e = tid + k * NTHR;
        const int lr = e / NXI, c = e - lr * NXI;
        const int gr = gr0 + lr;
        const int ce = e + NXI;
        const float uc = preg[k];
        const float um = (gr == 0)       ? uc : slabP[ce - NXI];
        const float ud = (gr == NXI - 1) ? uc : slabP[ce + NXI];
        const float ul = (c == 0)        ? uc : slabP[ce - 1];
        const float ur = (c == NXI - 1)  ? uc : slabP[ce + 1];
        const float vv = cboo_r[k] * uc + cbmo_r[k] * um + cbom_r[k] * ul + cbop_r[k] * ur + cbpo_r[k] * ud;
        vreg[k] = vv;
        if (lr == 0)  astoref(ghv_own + c, vv);
        if (lr == 11) astoref(ghv_own + NXI + c, vv);
        d[0] += (double)vv * (double)r0reg[k];      // sigma
        d[1] += (double)vv * (double)vv;            // <v,v>
        d[2] += (double)rreg[k] * (double)r0reg[k]; // rho
        d[3] += (double)rreg[k] * (double)vv;       // <r,v>
        d[4] += (double)rreg[k] * (double)rreg[k];  // <r,r>
      }
      bredN(d, 5, slots, 0, sys, bs, tid);
    }
    double s[5];
    sys_bar_collect(flags, &bphase, tid, bs, slots, 0, 5, sys, s);  // B (+collect)

    // ==== P2: wave0 scalars || waves1-7 receive v ghosts; then branch ====
    if (tid < 64) {
      const float sigma = (float)s[0];
      const float v_abs = froguard(s[1]);
      const float rho_l = (float)s[2];
      const float r0a = (it == 0) ? froguard(s[4]) : sh_r0abs;
      int code = 0;
      float al = 0.f, ra = 0.f;
      double ss2 = 0.0;
      if (it == 0 && !(r0a > THRC)) {
        code = 3; ra = r0a;
      } else if (sigma <= 1e-9f * v_abs * r0a) {
        code = 1;
      } else {
        al = rho_l / sigma;
        const double da = (double)al;
        ss2 = s[4] - 2.0 * da * s[3] + da * da * s[1];   // <s,s> analytic
        const float s_abs = froguard(ss2);
        if (s_abs <= THRC) { code = 2; ra = s_abs; }
      }
      if (lane == 0) {
        bci[0] = code; bcf[0] = al;
        if (code == 2 || code == 3) bcf[3] = ra;
        sh_ss2 = ss2; sh_rho = rho_l;
        if (it == 0) sh_r0abs = r0a;
      }
    } else {
      for (int g = tid - 64; g < 2 * NXI; g += NTHR - 64) {
        const bool top = g < NXI;
        const int c = top ? g : g - NXI;
        if (top) { if (bs > 0)       vgh[g] = aloadf(ghv + (size_t)(bs - 1) * 2 * NXI + NXI + c); }
        else     { if (bs < BPS - 1) vgh[g] = aloadf(ghv + (size_t)(bs + 1) * 2 * NXI + c); }
      }
    }
    __syncthreads();
    const int code = bci[0];

    if (code == 3) continue;          // converged at init: x stays mb; top breaks

    if (code == 1) {
      // ---- restart: p = r = r0 = mb - A x (explicit 1-row exchanges) ----
#pragma unroll
      for (int k = 0; k < EPT; k++) {
        const int e = tid + k * NTHR;
        const int lr = e / NXI, c = e - lr * NXI;
        slabS[e + NXI] = xreg[k];
        if (lr == 0)  astoref(ghx_own + c, xreg[k]);
        if (lr == 11) astoref(ghx_own + NXI + c, xreg[k]);
      }
      sys_bar(flags, &bphase, tid, bs);  // R1
      for (int g = tid; g < 2 * NXI; g += NTHR) {
        const bool top = g < NXI;
        const int c = top ? g : g - NXI;
        if (top) { if (bs > 0)       slabS[c]            = aloadf(ghx + (size_t)(bs - 1) * 2 * NXI + NXI + c); }
        else     { if (bs < BPS - 1) slabS[13 * NXI + c] = aloadf(ghx + (size_t)(bs + 1) * 2 * NXI + c); }
      }
      __syncthreads();
#pragma unroll
      for (int k = 0; k < EPT; k++) {
        const int e = tid + k * NTHR;
        const int lr = e / NXI, c = e - lr * NXI;
        const int gr = gr0 + lr;
        const int ce = e + NXI;
        const float uc = xreg[k];
        const float um = (gr == 0)       ? uc : slabS[ce - NXI];
        const float ud = (gr == NXI - 1) ? uc : slabS[ce + NXI];
        const float ul = (c == 0)        ? uc : slabS[ce - 1];
        const float ur = (c == NXI - 1)  ? uc : slabS[ce + 1];
        treg[k] = mb - (cboo_r[k] * uc + cbmo_r[k] * um + cbom_r[k] * ul + cbop_r[k] * ur + cbpo_r[k] * ud);
      }
      __syncthreads();  // all x reads done
      {
        double pp = 0;
#pragma unroll
        for (int k = 0; k < EPT; k++) {
          const int e = tid + k * NTHR;
          const int lr = e / NXI, c = e - lr * NXI;
          const float pn = treg[k];
          preg[k] = pn; rreg[k] = pn; r0reg[k] = pn;
          slabP[e + NXI] = pn;
          if (lr == 0)  astoref(ghq_own + c, pn);
          if (lr == 11) astoref(ghq_own + NXI + c, pn);
          pp += (double)pn * (double)pn;
        }
        bredN(&pp, 1, slots, 10, sys, bs, tid);
      }
      sys_bar(flags, &bphase, tid, bs);  // R2
      if (tid < 64) {
        double sp[1]; shredN(slots, 10, 1, sys, lane, sp);
        const float ra = froguard(sp[0]);
        if (lane == 0) { bcf[3] = ra; sh_r0abs = ra; }
      } else {
        for (int g = tid - 64; g < 2 * NXI; g += NTHR - 64) {
          const bool top = g < NXI;
          const int c = top ? g : g - NXI;
          const int ci = top ? c : 13 * NXI + c;
          if (top ? (bs > 0) : (bs < BPS - 1)) {
            const float pn = top ? aloadf(ghq + (size_t)(bs - 1) * 2 * NXI + NXI + c)
                                 : aloadf(ghq + (size_t)(bs + 1) * 2 * NXI + c);
            slabP[ci] = pn;
            rgh[g] = pn;
          }
        }
      }
      continue;   // loop-top syncthreads publishes bcf + slabs
    }

    const float alpha = bcf[0];
    if (code == 2) {
      // C3: x += alpha*p ; r = s (terminal: top breaks next round)
#pragma unroll
      for (int k = 0; k < EPT; k++) {
        xreg[k] = xreg[k] + alpha * preg[k];
        rreg[k] = rreg[k] - alpha * vreg[k];
      }
      continue;
    }

    // ---- s -> slabS (own rows + ghost rows from rgh - alpha*vgh) ----
#pragma unroll
    for (int k = 0; k < EPT; k++) {
      const int e = tid + k * NTHR;
      slabS[e + NXI] = rreg[k] - alpha * vreg[k];
    }
    for (int g = tid; g < 2 * NXI; g += NTHR) {
      const bool top = g < NXI;
      if (top ? (bs > 0) : (bs < BPS - 1)) {
        const int c = top ? g : g - NXI;
        const int ci = top ? c : 13 * NXI + c;
        slabS[ci] = rgh[g] - alpha * vgh[g];
      }
    }
    __syncthreads();
    // ---- t = A s ; publish t rows 0/11 ; 4 dots ----
    {
      double d[4] = {0, 0, 0, 0};
#pragma unroll
      for (int k = 0; k < EPT; k++) {
        const int e = tid + k * NTHR;
        const int lr = e / NXI, c = e - lr * NXI;
        const int gr = gr0 + lr;
        const int ce = e + NXI;
        const float sc = rreg[k] - alpha * vreg[k];
        const float um = (gr == 0)       ? sc : slabS[ce - NXI];
        const float ud = (gr == NXI - 1) ? sc : slabS[ce + NXI];
        const float ul = (c == 0)        ? sc : slabS[ce - 1];
        const float ur = (c == NXI - 1)  ? sc : slabS[ce + 1];
        const float tv = cboo_r[k] * sc + cbmo_r[k] * um + cbom_r[k] * ul + cbop_r[k] * ur + cbpo_r[k] * ud;
        treg[k] = tv;
        if (lr == 0)  astoref(ght_own + c, tv);
        if (lr == 11) astoref(ght_own + NXI + c, tv);
        d[0] += (double)tv * (double)tv;          // <t,t>
        d[1] += (double)tv * (double)sc;          // <t,s>
        d[2] += (double)sc * (double)r0reg[k];    // <s,r0>
        d[3] += (double)tv * (double)r0reg[k];    // <t,r0>
      }
      bredN(d, 4, slots, 5, sys, bs, tid);
    }
    double s2[4];
    sys_bar_collect(flags, &bphase, tid, bs, slots, 5, 4, sys, s2);  // C (+collect)

    // ==== P3: wave0 scalars || waves1-7 receive t ghosts; then update ====
    if (tid < 64) {
      const double tt = s2[0], ts = s2[1], sr0 = s2[2], tr0 = s2[3];
      const float om = (float)ts / (float)tt;
      const double dw = (double)om;
      const float rho_new = (float)(sr0 - dw * tr0);
      const double rr_new = sh_ss2 - 2.0 * dw * ts + dw * dw * tt;
      const float be = (bcf[0] / om) * (rho_new / sh_rho);
      if (lane == 0) {
        bcf[1] = om; bcf[2] = be; bcf[3] = froguard(rr_new);
      }
    } else {
      for (int g = tid - 64; g < 2 * NXI; g += NTHR - 64) {
        const bool top = g < NXI;
        const int c = top ? g : g - NXI;
        if (top) { if (bs > 0)       tgh[g] = aloadf(ght + (size_t)(bs - 1) * 2 * NXI + NXI + c); }
        else     { if (bs < BPS - 1) tgh[g] = aloadf(ght + (size_t)(bs + 1) * 2 * NXI + c); }
      }
    }
    __syncthreads();
    {
      const float omega = bcf[1];
      const float beta  = bcf[2];
#pragma unroll
      for (int k = 0; k < EPT; k++) {
        const int e = tid + k * NTHR;
        const float sc = rreg[k] - alpha * vreg[k];
        xreg[k] = xreg[k] + alpha * preg[k] + omega * sc;
        const float rn = sc - omega * treg[k];
        const float pn = rn + beta * (preg[k] - omega * vreg[k]);
        rreg[k] = rn;
        preg[k] = pn;
        slabP[e + NXI] = pn;
      }
      // ghost maintenance (rows -1, 12): bit-identical to neighbors' own rows
      for (int g = tid; g < 2 * NXI; g += NTHR) {
        const bool top = g < NXI;
        if (top ? (bs > 0) : (bs < BPS - 1)) {
          const int c = top ? g : g - NXI;
          const int ci = top ? c : 13 * NXI + c;
          const float sg = slabS[ci];
          const float rg_new = sg - omega * tgh[g];
          const float pg_new = rg_new + beta * (slabP[ci] - omega * vgh[g]);
          rgh[g] = rg_new;
          slabP[ci] = pg_new;
        }
      }
    }
    // no barrier: next P1 reads only block-local LDS (loop-top syncthreads)
  }

  // final write-out of x
#pragma unroll
  for (int k = 0; k < EPT; k++) {
    xs[tid + k * NTHR] = xreg[k];
  }
}

extern "C" void kernel_launch(void* const* d_in, const int* in_sizes, int n_in,
                              void* d_out, int out_size, void* d_ws, size_t ws_size,
                              hipStream_t stream) {
  const float* V  = (const float*)d_in[0];
  const float* M1 = (const float*)d_in[1];
  const float* M2 = (const float*)d_in[2];
  float* xout = (float*)d_out;
  float* wsf  = (float*)d_ws;
  hipMemsetAsync(d_ws, 0, 65536, stream);   // covers 16K flags + 32K slots
  bicg_kernel<<<dim3(NBLK), dim3(NTHR), 0, stream>>>(V, M1, M2, xout, wsf);
}

// Round 11
// 431.648 us; speedup vs baseline: 1.1208x; 1.1208x over previous
//
// R11 = exact revert to R9 (best measured: 347 µs typical dispatch).
// R10's fused barrier+collect regressed (+24%): prefetching the 31 early
// blocks' slots doesn't help because the LAST block's flag->slot-read chain
// is the critical path and cannot be prefetched; the fatter poll loop and
// +4 VGPR made every barrier slower.
#include <hip/hip_runtime.h>

#define NXI 384
#define NG  (NXI*NXI)          // 147456 elements per system
#define NSYS 8
#define BPS 32                 // blocks per system
#define NBLK (NSYS*BPS)        // 256 blocks
#define NTHR 512               // proven geometry: ~124 VGPR, zero spill
#define ROWS_PB 12             // rows per block
#define EPB (ROWS_PB*NXI)      // 4608 elements per block
#define EPT (EPB/NTHR)         // 9 elements per thread

// thr = EPS*NX*NY = 1e-9*147456
#define THRC 1.47456e-4f

// ---- workspace layout (all blocks' barrier state in PRIVATE cache lines) ----
// bytes [0, 16K):  flags — one 64B line per block: flag(sys,bs) at u32 index (sys*BPS+bs)*16
// bytes [16K,48K): slots — one 128B record per block: rec(sys,bs)[16 doubles], channel=idx
// bytes [48K,...): ghost rows (v,t,x,p boundary exchanges)

// ---- relaxed agent-scope accessors ----
__device__ __forceinline__ float aloadf(const float* p) {
  return __hip_atomic_load(p, __ATOMIC_RELAXED, __HIP_MEMORY_SCOPE_AGENT);
}
__device__ __forceinline__ void astoref(float* p, float v) {
  __hip_atomic_store(p, v, __ATOMIC_RELAXED, __HIP_MEMORY_SCOPE_AGENT);
}
__device__ __forceinline__ double aloadd(const double* p) {
  return __hip_atomic_load(p, __ATOMIC_RELAXED, __HIP_MEMORY_SCOPE_AGENT);
}
__device__ __forceinline__ void astored(double* p, double v) {
  __hip_atomic_store(p, v, __ATOMIC_RELAXED, __HIP_MEMORY_SCOPE_AGENT);
}

__device__ __forceinline__ double wave_red(double v) {
#pragma unroll
  for (int off = 32; off > 0; off >>= 1) v += __shfl_down(v, off, 64);
  return v;
}

// ---- per-system flag barrier (validated protocol; R8 sticky poll) ----
// Flags 64B-padded: block's flag store touches ONLY its own LLC line.
__device__ __forceinline__ void sys_bar(unsigned* flags, unsigned* phase, int tid, int bs) {
  __atomic_signal_fence(__ATOMIC_SEQ_CST);
  __builtin_amdgcn_s_waitcnt(0);
  __syncthreads();
  const unsigned ph = ++(*phase);
  if (tid == 0) {
    __hip_atomic_store(flags + (size_t)bs * 16, ph, __ATOMIC_RELAXED, __HIP_MEMORY_SCOPE_AGENT);
  }
  if (tid < 64) {
    bool done = false;
    while (true) {
      if (!done) {
        const unsigned f = __hip_atomic_load(flags + (size_t)(tid & 31) * 16,
                                             __ATOMIC_RELAXED, __HIP_MEMORY_SCOPE_AGENT);
        done = (f >= ph);
      }
      if (__ballot(done) == ~0ull) break;
      __builtin_amdgcn_s_sleep(2);
    }
  }
  __syncthreads();
  __atomic_signal_fence(__ATOMIC_SEQ_CST);
}

// Block-reduce n<=5 doubles into this block's PRIVATE 128B slot record.
// Channel q -> record word (chan0+q). Lane q sums channel q (same order as the
// original tid0 loop -> bit-identical). No trailing syncthreads: every call
// site is immediately followed by sys_bar (waitcnt+barrier supply the guard;
// all slot stores are wave0's, drained by wave0's s_waitcnt before flag store).
__device__ __forceinline__ void bredN(const double* v, int n,
                                      double* slots, int chan0,
                                      int sys, int bs, int tid) {
  __shared__ double sred[NTHR/64][5];
  const int wid = tid >> 6, lane = tid & 63;
#pragma unroll
  for (int q = 0; q < n; q++) {
    const double w = wave_red(v[q]);
    if (lane == 0) sred[wid][q] = w;
  }
  __syncthreads();
  if (tid < n) {
    double a = 0.0;
#pragma unroll
    for (int w2 = 0; w2 < NTHR/64; w2++) a += sred[w2][tid];
    astored(slots + (size_t)(sys * BPS + bs) * 16 + (chan0 + tid), a);
  }
}

// Butterfly sums of n channels (bit-exact identical in every lane/block).
__device__ __forceinline__ void shredN(const double* slots, int chan0, int n,
                                       int sys, int lane, double* out) {
  double v[5];
#pragma unroll
  for (int q = 0; q < n; q++)
    v[q] = aloadd(slots + (size_t)(sys * BPS + (lane & 31)) * 16 + (chan0 + q));
#pragma unroll
  for (int q = 0; q < n; q++) {
    double x = v[q];
    x += __shfl_xor(x, 1, 64);
    x += __shfl_xor(x, 2, 64);
    x += __shfl_xor(x, 4, 64);
    x += __shfl_xor(x, 8, 64);
    x += __shfl_xor(x, 16, 64);
    out[q] = x;
  }
}

__device__ __forceinline__ float froguard(double sq) {
  return sq > 0.0 ? (float)sqrt(sq) : 0.0f;
}

// Compute the 5 stencil coefficients at global (row i, col j).
// c5: 0=boo 1=bmo 2=bom 3=bop 4=bpo
__device__ __forceinline__ void coef5(const float* __restrict__ Vb,
                                      const float* __restrict__ M1b,
                                      const float* __restrict__ M2b,
                                      int i, int j, float* c5) {
  const int a0 = (i - 1 < 0) ? 0 : i - 1;
  const int a2 = (i + 1 > NXI - 1) ? NXI - 1 : i + 1;
  const int b0 = (j - 1 < 0) ? 0 : j - 1;
  const int b2 = (j + 1 > NXI - 1) ? NXI - 1 : j + 1;
  const float vc = Vb[j * NXI + i] + 1.0f;
  const float vu = Vb[j * NXI + a0] + 1.0f;
  const float vd = Vb[j * NXI + a2] + 1.0f;
  const float vl = Vb[b0 * NXI + i] + 1.0f;
  const float vr = Vb[b2 * NXI + i] + 1.0f;
  const float D1A = M1b[j * NXI + i] * ((vd - vc) / (0.5f * (vd + vc)));
  const float D1B = M1b[j * NXI + a0] * ((vc - vu) / (0.5f * (vc + vu)));
  const float D2A = M2b[j * NXI + i] * ((vr - vc) / (0.5f * (vr + vc)));
  const float D2B = M2b[b0 * NXI + i] * ((vc - vl) / (0.5f * (vc + vl)));
  c5[0] = 41.0f - 5.0f * (D1B - D1A) - 5.0f * (D2B - D2A);
  c5[1] = -10.0f - 5.0f * D1B;
  c5[2] = -10.0f - 5.0f * D2B;
  c5[3] = -10.0f + 5.0f * D2A;
  c5[4] = -10.0f + 5.0f * D1A;
}

__global__ __launch_bounds__(NTHR, 1) void bicg_kernel(
    const float* __restrict__ V, const float* __restrict__ M1, const float* __restrict__ M2,
    float* __restrict__ xout, float* __restrict__ wsf) {
  const int blk = blockIdx.x;
  const int sys = blk & (NSYS - 1);
  const int bs  = blk >> 3;
  const int tid = threadIdx.x;
  const int lane = tid & 63;
  const int gr0 = bs * ROWS_PB;

  // ---- LDS (~53 KB): rows -1..12 -> index (r+1)*NXI ----
  __shared__ float slabP[14 * NXI];   // p (own + 1 ghost row/side)
  __shared__ float slabS[14 * NXI];   // s (own + ghost); x staging during restart
  __shared__ float vgh[2 * NXI];      // received v ghosts: [0..NXI)=row -1, rest=row 12
  __shared__ float tgh[2 * NXI];      // received t ghosts
  __shared__ float rgh[2 * NXI];      // maintained r ghosts (recursive, bit-exact)
  __shared__ float bcf[4];            // 0:alpha 1:omega 2:beta 3:r_abs
  __shared__ int   bci[1];            // 0 normal, 1 RES, 2 C3, 3 converged-at-init
  __shared__ float sh_r0abs, sh_rho;
  __shared__ double sh_ss2;

  // ---- workspace (private-line layout; see header comment) ----
  unsigned* flags = (unsigned*)wsf + (size_t)sys * BPS * 16;  // 64B per flag
  double* slots = (double*)(wsf + 4096);                      // 128B record per block
  float* ghv_all = wsf + 12288;                               // [sys][bs][2][NXI] v boundary
  float* ght_all = ghv_all + (size_t)NSYS * BPS * 2 * NXI;    // t boundary
  float* ghx_all = ght_all + (size_t)NSYS * BPS * 2 * NXI;    // x boundary (restart)
  float* ghq_all = ghx_all + (size_t)NSYS * BPS * 2 * NXI;    // p boundary (restart)
  float* ghv = ghv_all + (size_t)sys * BPS * 2 * NXI;
  float* ght = ght_all + (size_t)sys * BPS * 2 * NXI;
  float* ghx = ghx_all + (size_t)sys * BPS * 2 * NXI;
  float* ghq = ghq_all + (size_t)sys * BPS * 2 * NXI;
  float* ghv_own = ghv + (size_t)bs * 2 * NXI;      // [0]=row0, [NXI]=row11
  float* ght_own = ght + (size_t)bs * 2 * NXI;
  float* ghx_own = ghx + (size_t)bs * 2 * NXI;
  float* ghq_own = ghq + (size_t)bs * 2 * NXI;

  unsigned bphase = 0;

  const size_t so = (size_t)sys * NG;
  const float* Vb  = V  + so;
  const float* M1b = M1 + so;
  const float* M2b = M2 + so;
  float* xs = xout + so + (size_t)bs * EPB;

  // ---------- Phase 0: own-element coeffs -> REGISTERS + V-mean partial ----------
  float cboo_r[EPT], cbmo_r[EPT], cbom_r[EPT], cbop_r[EPT], cbpo_r[EPT];
#pragma unroll
  for (int k = 0; k < EPT; k++) {
    const int e = tid + k * NTHR;
    const int lr = e / NXI, c = e - lr * NXI;
    float c5[5];
    coef5(Vb, M1b, M2b, gr0 + lr, c, c5);
    cboo_r[k] = c5[0]; cbmo_r[k] = c5[1]; cbom_r[k] = c5[2];
    cbop_r[k] = c5[3]; cbpo_r[k] = c5[4];
  }
  {
    double vsum = 0.0;
#pragma unroll
    for (int k = 0; k < EPT; k++) vsum += (double)Vb[bs * EPB + tid + k * NTHR];
    bredN(&vsum, 1, slots, 9, sys, bs, tid);
  }
  sys_bar(flags, &bphase, tid, bs);  // S0 (only setup barrier)

  // ---------- Init: x=mb; p=r=r0 = mb - rowsum*mb on own AND ghost rows ----------
  double smb[1]; shredN(slots, 9, 1, sys, lane, smb);
  const float mb = (float)(smb[0] / (double)NG) + 1.0f;
  float preg[EPT], rreg[EPT], r0reg[EPT], vreg[EPT], treg[EPT], xreg[EPT];
#pragma unroll
  for (int k = 0; k < EPT; k++) {
    const int e = tid + k * NTHR;
    const int ce = e + NXI;
    const float ax = (cboo_r[k] + cbmo_r[k] + cbom_r[k] + cbop_r[k] + cbpo_r[k]) * mb;
    const float pn = mb - ax;
    xreg[k] = mb;
    preg[k] = pn; rreg[k] = pn; r0reg[k] = pn;
    slabP[ce] = pn;
  }
  for (int g = tid; g < 2 * NXI; g += NTHR) {
    const bool top = g < NXI;
    if (top ? (bs > 0) : (bs < BPS - 1)) {
      const int c = top ? g : g - NXI;
      const int ci = top ? c : 13 * NXI + c;     // row -1 / row 12 index
      const int gi = top ? gr0 - 1 : gr0 + ROWS_PB;
      float c5[5];
      coef5(Vb, M1b, M2b, gi, c, c5);            // one-time ghost coeff recompute
      const float pn = mb - (c5[0] + c5[1] + c5[2] + c5[3] + c5[4]) * mb;
      slabP[ci] = pn;
      rgh[g] = pn;
    }
  }
  if (tid == 0) { bcf[3] = 1.0f; bci[0] = 0; }

  for (int it = 0; it < 30; ++it) {
    __syncthreads();                 // bcf/slab writes visible
    if (!(bcf[3] > THRC)) break;     // uniform within system

    // ==== P1: v = A p own rows; publish v rows 0/11; 5 dots ====
    {
      double d[5] = {0, 0, 0, 0, 0};
#pragma unroll
      for (int k = 0; k < EPT; k++) {
        const int e = tid + k * NTHR;
        const int lr = e / NXI, c = e - lr * NXI;
        const int gr = gr0 + lr;
        const int ce = e + NXI;
        const float uc = preg[k];
        const float um = (gr == 0)       ? uc : slabP[ce - NXI];
        const float ud = (gr == NXI - 1) ? uc : slabP[ce + NXI];
        const float ul = (c == 0)        ? uc : slabP[ce - 1];
        const float ur = (c == NXI - 1)  ? uc : slabP[ce + 1];
        const float vv = cboo_r[k] * uc + cbmo_r[k] * um + cbom_r[k] * ul + cbop_r[k] * ur + cbpo_r[k] * ud;
        vreg[k] = vv;
        if (lr == 0)  astoref(ghv_own + c, vv);
        if (lr == 11) astoref(ghv_own + NXI + c, vv);
        d[0] += (double)vv * (double)r0reg[k];      // sigma
        d[1] += (double)vv * (double)vv;            // <v,v>
        d[2] += (double)rreg[k] * (double)r0reg[k]; // rho
        d[3] += (double)rreg[k] * (double)vv;       // <r,v>
        d[4] += (double)rreg[k] * (double)rreg[k];  // <r,r>
      }
      bredN(d, 5, slots, 0, sys, bs, tid);
    }
    sys_bar(flags, &bphase, tid, bs);  // B

    // ==== P2: wave0 scalars || waves1-7 receive v ghosts; then branch ====
    if (tid < 64) {
      double s[5];
      shredN(slots, 0, 5, sys, lane, s);
      const float sigma = (float)s[0];
      const float v_abs = froguard(s[1]);
      const float rho_l = (float)s[2];
      const float r0a = (it == 0) ? froguard(s[4]) : sh_r0abs;
      int code = 0;
      float al = 0.f, ra = 0.f;
      double ss2 = 0.0;
      if (it == 0 && !(r0a > THRC)) {
        code = 3; ra = r0a;
      } else if (sigma <= 1e-9f * v_abs * r0a) {
        code = 1;
      } else {
        al = rho_l / sigma;
        const double da = (double)al;
        ss2 = s[4] - 2.0 * da * s[3] + da * da * s[1];   // <s,s> analytic
        const float s_abs = froguard(ss2);
        if (s_abs <= THRC) { code = 2; ra = s_abs; }
      }
      if (lane == 0) {
        bci[0] = code; bcf[0] = al;
        if (code == 2 || code == 3) bcf[3] = ra;
        sh_ss2 = ss2; sh_rho = rho_l;
        if (it == 0) sh_r0abs = r0a;
      }
    } else {
      for (int g = tid - 64; g < 2 * NXI; g += NTHR - 64) {
        const bool top = g < NXI;
        const int c = top ? g : g - NXI;
        if (top) { if (bs > 0)       vgh[g] = aloadf(ghv + (size_t)(bs - 1) * 2 * NXI + NXI + c); }
        else     { if (bs < BPS - 1) vgh[g] = aloadf(ghv + (size_t)(bs + 1) * 2 * NXI + c); }
      }
    }
    __syncthreads();
    const int code = bci[0];

    if (code == 3) continue;          // converged at init: x stays mb; top breaks

    if (code == 1) {
      // ---- restart: p = r = r0 = mb - A x (explicit 1-row exchanges) ----
#pragma unroll
      for (int k = 0; k < EPT; k++) {
        const int e = tid + k * NTHR;
        const int lr = e / NXI, c = e - lr * NXI;
        slabS[e + NXI] = xreg[k];
        if (lr == 0)  astoref(ghx_own + c, xreg[k]);
        if (lr == 11) astoref(ghx_own + NXI + c, xreg[k]);
      }
      sys_bar(flags, &bphase, tid, bs);  // R1
      for (int g = tid; g < 2 * NXI; g += NTHR) {
        const bool top = g < NXI;
        const int c = top ? g : g - NXI;
        if (top) { if (bs > 0)       slabS[c]            = aloadf(ghx + (size_t)(bs - 1) * 2 * NXI + NXI + c); }
        else     { if (bs < BPS - 1) slabS[13 * NXI + c] = aloadf(ghx + (size_t)(bs + 1) * 2 * NXI + c); }
      }
      __syncthreads();
#pragma unroll
      for (int k = 0; k < EPT; k++) {
        const int e = tid + k * NTHR;
        const int lr = e / NXI, c = e - lr * NXI;
        const int gr = gr0 + lr;
        const int ce = e + NXI;
        const float uc = xreg[k];
        const float um = (gr == 0)       ? uc : slabS[ce - NXI];
        const float ud = (gr == NXI - 1) ? uc : slabS[ce + NXI];
        const float ul = (c == 0)        ? uc : slabS[ce - 1];
        const float ur = (c == NXI - 1)  ? uc : slabS[ce + 1];
        treg[k] = mb - (cboo_r[k] * uc + cbmo_r[k] * um + cbom_r[k] * ul + cbop_r[k] * ur + cbpo_r[k] * ud);
      }
      __syncthreads();  // all x reads done
      {
        double pp = 0;
#pragma unroll
        for (int k = 0; k < EPT; k++) {
          const int e = tid + k * NTHR;
          const int lr = e / NXI, c = e - lr * NXI;
          const float pn = treg[k];
          preg[k] = pn; rreg[k] = pn; r0reg[k] = pn;
          slabP[e + NXI] = pn;
          if (lr == 0)  astoref(ghq_own + c, pn);
          if (lr == 11) astoref(ghq_own + NXI + c, pn);
          pp += (double)pn * (double)pn;
        }
        bredN(&pp, 1, slots, 10, sys, bs, tid);
      }
      sys_bar(flags, &bphase, tid, bs);  // R2
      if (tid < 64) {
        double sp[1]; shredN(slots, 10, 1, sys, lane, sp);
        const float ra = froguard(sp[0]);
        if (lane == 0) { bcf[3] = ra; sh_r0abs = ra; }
      } else {
        for (int g = tid - 64; g < 2 * NXI; g += NTHR - 64) {
          const bool top = g < NXI;
          const int c = top ? g : g - NXI;
          const int ci = top ? c : 13 * NXI + c;
          if (top ? (bs > 0) : (bs < BPS - 1)) {
            const float pn = top ? aloadf(ghq + (size_t)(bs - 1) * 2 * NXI + NXI + c)
                                 : aloadf(ghq + (size_t)(bs + 1) * 2 * NXI + c);
            slabP[ci] = pn;
            rgh[g] = pn;
          }
        }
      }
      continue;   // loop-top syncthreads publishes bcf + slabs
    }

    const float alpha = bcf[0];
    if (code == 2) {
      // C3: x += alpha*p ; r = s (terminal: top breaks next round)
#pragma unroll
      for (int k = 0; k < EPT; k++) {
        xreg[k] = xreg[k] + alpha * preg[k];
        rreg[k] = rreg[k] - alpha * vreg[k];
      }
      continue;
    }

    // ---- s -> slabS (own rows + ghost rows from rgh - alpha*vgh) ----
#pragma unroll
    for (int k = 0; k < EPT; k++) {
      const int e = tid + k * NTHR;
      slabS[e + NXI] = rreg[k] - alpha * vreg[k];
    }
    for (int g = tid; g < 2 * NXI; g += NTHR) {
      const bool top = g < NXI;
      if (top ? (bs > 0) : (bs < BPS - 1)) {
        const int c = top ? g : g - NXI;
        const int ci = top ? c : 13 * NXI + c;
        slabS[ci] = rgh[g] - alpha * vgh[g];
      }
    }
    __syncthreads();
    // ---- t = A s ; publish t rows 0/11 ; 4 dots ----
    {
      double d[4] = {0, 0, 0, 0};
#pragma unroll
      for (int k = 0; k < EPT; k++) {
        const int e = tid + k * NTHR;
        const int lr = e / NXI, c = e - lr * NXI;
        const int gr = gr0 + lr;
        const int ce = e + NXI;
        const float sc = rreg[k] - alpha * vreg[k];
        const float um = (gr == 0)       ? sc : slabS[ce - NXI];
        const float ud = (gr == NXI - 1) ? sc : slabS[ce + NXI];
        const float ul = (c == 0)        ? sc : slabS[ce - 1];
        const float ur = (c == NXI - 1)  ? sc : slabS[ce + 1];
        const float tv = cboo_r[k] * sc + cbmo_r[k] * um + cbom_r[k] * ul + cbop_r[k] * ur + cbpo_r[k] * ud;
        treg[k] = tv;
        if (lr == 0)  astoref(ght_own + c, tv);
        if (lr == 11) astoref(ght_own + NXI + c, tv);
        d[0] += (double)tv * (double)tv;          // <t,t>
        d[1] += (double)tv * (double)sc;          // <t,s>
        d[2] += (double)sc * (double)r0reg[k];    // <s,r0>
        d[3] += (double)tv * (double)r0reg[k];    // <t,r0>
      }
      bredN(d, 4, slots, 5, sys, bs, tid);
    }
    sys_bar(flags, &bphase, tid, bs);  // C

    // ==== P3: wave0 scalars || waves1-7 receive t ghosts; then update ====
    if (tid < 64) {
      double s2[4];
      shredN(slots, 5, 4, sys, lane, s2);
      const double tt = s2[0], ts = s2[1], sr0 = s2[2], tr0 = s2[3];
      const float om = (float)ts / (float)tt;
      const double dw = (double)om;
      const float rho_new = (float)(sr0 - dw * tr0);
      const double rr_new = sh_ss2 - 2.0 * dw * ts + dw * dw * tt;
      const float be = (bcf[0] / om) * (rho_new / sh_rho);
      if (lane == 0) {
        bcf[1] = om; bcf[2] = be; bcf[3] = froguard(rr_new);
      }
    } else {
      for (int g = tid - 64; g < 2 * NXI; g += NTHR - 64) {
        const bool top = g < NXI;
        const int c = top ? g : g - NXI;
        if (top) { if (bs > 0)       tgh[g] = aloadf(ght + (size_t)(bs - 1) * 2 * NXI + NXI + c); }
        else     { if (bs < BPS - 1) tgh[g] = aloadf(ght + (size_t)(bs + 1) * 2 * NXI + c); }
      }
    }
    __syncthreads();
    {
      const float omega = bcf[1];
      const float beta  = bcf[2];
#pragma unroll
      for (int k = 0; k < EPT; k++) {
        const int e = tid + k * NTHR;
        const float sc = rreg[k] - alpha * vreg[k];
        xreg[k] = xreg[k] + alpha * preg[k] + omega * sc;
        const float rn = sc - omega * treg[k];
        const float pn = rn + beta * (preg[k] - omega * vreg[k]);
        rreg[k] = rn;
        preg[k] = pn;
        slabP[e + NXI] = pn;
      }
      // ghost maintenance (rows -1, 12): bit-identical to neighbors' own rows
      for (int g = tid; g < 2 * NXI; g += NTHR) {
        const bool top = g < NXI;
        if (top ? (bs > 0) : (bs < BPS - 1)) {
          const int c = top ? g : g - NXI;
          const int ci = top ? c : 13 * NXI + c;
          const float sg = slabS[ci];
          const float rg_new = sg - omega * tgh[g];
          const float pg_new = rg_new + beta * (slabP[ci] - omega * vgh[g]);
          rgh[g] = rg_new;
          slabP[ci] = pg_new;
        }
      }
    }
    // no barrier: next P1 reads only block-local LDS (loop-top syncthreads)
  }

  // final write-out of x
#pragma unroll
  for (int k = 0; k < EPT; k++) {
    xs[tid + k * NTHR] = xreg[k];
  }
}

extern "C" void kernel_launch(void* const* d_in, const int* in_sizes, int n_in,
                              void* d_out, int out_size, void* d_ws, size_t ws_size,
                              hipStream_t stream) {
  const float* V  = (const float*)d_in[0];
  const float* M1 = (const float*)d_in[1];
  const float* M2 = (const float*)d_in[2];
  float* xout = (float*)d_out;
  float* wsf  = (float*)d_ws;
  hipMemsetAsync(d_ws, 0, 65536, stream);   // covers 16K flags + 32K slots
  bicg_kernel<<<dim3(NBLK), dim3(NTHR), 0, stream>>>(V, M1, M2, xout, wsf);
}